// Round 7
// baseline (799.810 us; speedup 1.0000x reference)
//
#include <hip/hip_runtime.h>
#include <cstddef>
#include <cstdint>

static constexpr int Bc   = 4;
static constexpr int Lq   = 4096;
static constexpr int Dm   = 1024;
static constexpr int Dmlp = 4096;
static constexpr int Mrows = Bc * Lq;   // 16384
static constexpr int Lk1   = Lq + 1;    // 4097

typedef unsigned short u16;
typedef __bf16 bf16_t;
typedef bf16_t bf16x8 __attribute__((ext_vector_type(8)));
typedef float  f32x4  __attribute__((ext_vector_type(4)));

__device__ __forceinline__ u16 f2b(float f) {
    uint32_t u = __builtin_bit_cast(uint32_t, f);
    return (u16)((u + 0x7FFFu + ((u >> 16) & 1u)) >> 16);
}
__device__ __forceinline__ float b2f(u16 h) {
    uint32_t u = ((uint32_t)h) << 16;
    return __builtin_bit_cast(float, u);
}

#define GLL16(gsrc, ldst) \
    __builtin_amdgcn_global_load_lds( \
        (const __attribute__((address_space(1))) void*)(gsrc), \
        (__attribute__((address_space(3))) void*)(ldst), 16, 0, 0)

// ---------------------------------------------------------------------------
__global__ __launch_bounds__(256)
void zero_kernel(float* __restrict__ p, int n) {
    const int i = blockIdx.x * 256 + threadIdx.x;
    if (i < n) p[i] = 0.0f;
}

__global__ __launch_bounds__(256)
void cvt_bf16_kernel(const float* __restrict__ in, u16* __restrict__ outp, int n) {
    for (int i = (blockIdx.x * 256 + threadIdx.x) * 4; i < n; i += gridDim.x * 256 * 4) {
        float4 v = *(const float4*)&in[i];
        ushort4 o = { f2b(v.x), f2b(v.y), f2b(v.z), f2b(v.w) };
        *(ushort4*)&outp[i] = o;
    }
}

// W [R][C] fp32 -> Wt [C][R] bf16
__global__ __launch_bounds__(256)
void transpose_bf16_kernel(const float* __restrict__ in, u16* __restrict__ outp,
                           int R, int C) {
    __shared__ float tile[64][65];
    const int r0 = blockIdx.y * 64, c0 = blockIdx.x * 64;
    const int t = threadIdx.x;
    const int lr = t >> 2, lc0 = (t & 3) * 16;
    #pragma unroll
    for (int j = 0; j < 4; ++j) {
        float4 v = *(const float4*)&in[(size_t)(r0 + lr) * C + c0 + lc0 + j * 4];
        tile[lr][lc0 + j * 4 + 0] = v.x;
        tile[lr][lc0 + j * 4 + 1] = v.y;
        tile[lr][lc0 + j * 4 + 2] = v.z;
        tile[lr][lc0 + j * 4 + 3] = v.w;
    }
    __syncthreads();
    const int oc = t >> 2, rr0 = (t & 3) * 16;
    union { u16 u[16]; uint4 v[2]; } pk;
    #pragma unroll
    for (int j = 0; j < 16; ++j) pk.u[j] = f2b(tile[rr0 + j][oc]);
    u16* po = &outp[(size_t)(c0 + oc) * R + r0 + rr0];
    *(uint4*)&po[0] = pk.v[0];
    *(uint4*)&po[8] = pk.v[1];
}

// KVT[bh][e][d] = bf16(KV[bh][d][e])
__global__ __launch_bounds__(256)
void kvt_cvt_kernel(const float* __restrict__ KV, u16* __restrict__ KVT) {
    const int bh = blockIdx.x;
    __shared__ float t[64][65];
    const int tid = threadIdx.x;
    const int r = tid >> 2, c0 = (tid & 3) * 16;
    const float* src = &KV[(size_t)bh * 4096];
    #pragma unroll
    for (int j = 0; j < 4; ++j) {
        float4 v = *(const float4*)&src[r * 64 + c0 + j * 4];
        t[r][c0 + j * 4 + 0] = v.x;
        t[r][c0 + j * 4 + 1] = v.y;
        t[r][c0 + j * 4 + 2] = v.z;
        t[r][c0 + j * 4 + 3] = v.w;
    }
    __syncthreads();
    const int e = tid >> 2, d0 = (tid & 3) * 16;
    union { u16 u[16]; uint4 v[2]; } pk;
    #pragma unroll
    for (int j = 0; j < 16; ++j) pk.u[j] = f2b(t[d0 + j][e]);
    u16* po = &KVT[(size_t)bh * 4096 + e * 64 + d0];
    *(uint4*)&po[0] = pk.v[0];
    *(uint4*)&po[8] = pk.v[1];
}

// ---------------------------------------------------------------------------
// 256x256 MFMA GEMM, 8-phase schedule (T2+T3+T4+T5): BK=64, dbuf x k-half
// pieces (16KB), per phase {ds_read || stage 1 piece -> bar -> lgkm0 ->
// setprio -> 16 MFMA -> bar}, counted vmcnt(8) twice per tile (never 0 in
// main loop). 8 waves (2M x 4N), per-wave 128x64 out. XCD block swizzle.
// ---------------------------------------------------------------------------
#define PH_SYNC() do { __builtin_amdgcn_s_barrier(); \
    asm volatile("s_waitcnt lgkmcnt(0)" ::: "memory"); \
    __builtin_amdgcn_sched_barrier(0); \
    __builtin_amdgcn_s_setprio(1); } while (0)
#define PH_END(wc) do { __builtin_amdgcn_s_setprio(0); \
    if ((wc) == 8) asm volatile("s_waitcnt vmcnt(8)" ::: "memory"); \
    else if ((wc) == 4) asm volatile("s_waitcnt vmcnt(4)" ::: "memory"); \
    else if ((wc) == 0) asm volatile("s_waitcnt vmcnt(0)" ::: "memory"); \
    __builtin_amdgcn_s_barrier(); } while (0)

template<int ACT, bool RES, bool ACCUM, bool BIAS, bool OBF16>
__global__ __launch_bounds__(512, 1)
void mfma_gemm256(const u16* __restrict__ A, int ldA,
                  const u16* __restrict__ Bt, int ldB,
                  const float* __restrict__ bias,
                  void* __restrict__ Cout,
                  const u16* __restrict__ res1, const float* __restrict__ res2,
                  int M, int N, int K) {
    __shared__ u16 ldsA[32768];   // 2 buf x 2 khalf x 8192 u16 (16KB pieces)
    __shared__ u16 ldsB[32768];
    const int tid = threadIdx.x;
    const int l   = tid & 63;
    const int w   = tid >> 6;
    const int wm  = w >> 2;
    const int wn  = w & 3;
    const int l16 = l & 15, l4 = l >> 4;

    const int gx = N >> 8;
    int bid = blockIdx.x;
    bid = (bid & 7) * ((int)gridDim.x >> 3) + (bid >> 3);
    const int brow = (bid / gx) << 8;
    const int bcol = (bid % gx) << 8;

    // --- staging precompute (linear LDS dest, inverse-swizzled global src) ---
    // piece = [128 lines][8 slot16]; LDS(L,s8) holds global row 2L+(lg>>2),
    // kslot lg&3, lg = s8 ^ (L&7). Thread t, issue j: L = j*64+(t>>3), s8=t&7.
    const int logi  = (tid & 7) ^ ((tid >> 3) & 7);
    const int srow0 = 2 * (tid >> 3) + (logi >> 2);    // + j*128
    const int skel  = (logi & 3) << 3;                 // k elem within k-half
    u16* sdstA = ldsA + tid * 8;                       // + piece_off + j*4096
    u16* sdstB = ldsB + tid * 8;

    // --- ds_read fragment precompute: row r, kslot l4 ->
    // line r>>1, phys = (l4+4*(r&1)) ^ ((r>>1)&7)
    const int lline = l16 >> 1;
    const int physd = (l4 + ((l16 & 1) << 2)) ^ lline;
    const int aBase = (wm * 64 + lline) * 64 + physd * 8;   // + m*512
    const int bBase = (wn * 32 + lline) * 64 + physd * 8;   // + n*512

    f32x4 acc[8][4];
    const f32x4 zf = {0.f, 0.f, 0.f, 0.f};
    #pragma unroll
    for (int m = 0; m < 8; ++m)
        #pragma unroll
        for (int n = 0; n < 4; ++n) acc[m][n] = zf;

    const int T_ = K >> 6;
    const int PMAX = 4 * T_;

    // piece idx: tile tau = idx>>2, sub: 0=A.k0 1=B.k0 2=A.k1 3=B.k1
    auto stage_piece = [&](int idx) {
        const int isB = idx & 1, kh = (idx >> 1) & 1, tau = idx >> 2;
        const int kof = tau * 64 + kh * 32 + skel;
        const int lof = (((tau & 1) << 1) | kh) * 8192;
        if (!isB) {
            const u16* g = A + (size_t)(brow + srow0) * ldA + kof;
            GLL16(g, sdstA + lof);
            GLL16(g + (size_t)128 * ldA, sdstA + lof + 4096);
        } else {
            const u16* g = Bt + (size_t)(bcol + srow0) * ldB + kof;
            GLL16(g, sdstB + lof);
            GLL16(g + (size_t)128 * ldB, sdstB + lof + 4096);
        }
    };

    auto do_tile = [&](int t, int buf, int w1, int w3) {
        const u16* A0 = ldsA + (buf * 2 + 0) * 8192;
        const u16* A1 = ldsA + (buf * 2 + 1) * 8192;
        const u16* B0 = ldsB + (buf * 2 + 0) * 8192;
        const u16* B1 = ldsB + (buf * 2 + 1) * 8192;
        const int base = 4 * t;
        bf16x8 afr[4], bfr[4];
        // ---- p0: kk0, m0-3 (reads B kk0 + A kk0 lo; stages A.k1(t+1)) ----
        #pragma unroll
        for (int n = 0; n < 4; ++n) bfr[n] = *(const bf16x8*)&B0[bBase + n * 512];
        #pragma unroll
        for (int m = 0; m < 4; ++m) afr[m] = *(const bf16x8*)&A0[aBase + m * 512];
        if (base + 6 < PMAX) stage_piece(base + 6);
        PH_SYNC();
        #pragma unroll
        for (int m = 0; m < 4; ++m)
            #pragma unroll
            for (int n = 0; n < 4; ++n)
                acc[m][n] = __builtin_amdgcn_mfma_f32_16x16x32_bf16(
                    afr[m], bfr[n], acc[m][n], 0, 0, 0);
        PH_END(-1);
        // ---- p1: kk0, m4-7 (stages B.k1(t+1); vmcnt protects t.k1 reads) ----
        #pragma unroll
        for (int m = 0; m < 4; ++m) afr[m] = *(const bf16x8*)&A0[aBase + (m + 4) * 512];
        if (base + 7 < PMAX) stage_piece(base + 7);
        PH_SYNC();
        #pragma unroll
        for (int m = 0; m < 4; ++m)
            #pragma unroll
            for (int n = 0; n < 4; ++n)
                acc[m + 4][n] = __builtin_amdgcn_mfma_f32_16x16x32_bf16(
                    afr[m], bfr[n], acc[m + 4][n], 0, 0, 0);
        PH_END(w1);
        // ---- p2: kk1, m0-3 (stages A.k0(t+2); its slot freed after p1) ----
        #pragma unroll
        for (int n = 0; n < 4; ++n) bfr[n] = *(const bf16x8*)&B1[bBase + n * 512];
        #pragma unroll
        for (int m = 0; m < 4; ++m) afr[m] = *(const bf16x8*)&A1[aBase + m * 512];
        if (base + 8 < PMAX) stage_piece(base + 8);
        PH_SYNC();
        #pragma unroll
        for (int m = 0; m < 4; ++m)
            #pragma unroll
            for (int n = 0; n < 4; ++n)
                acc[m][n] = __builtin_amdgcn_mfma_f32_16x16x32_bf16(
                    afr[m], bfr[n], acc[m][n], 0, 0, 0);
        PH_END(-1);
        // ---- p3: kk1, m4-7 (stages B.k0(t+2); vmcnt protects t+1.k0 reads) ----
        #pragma unroll
        for (int m = 0; m < 4; ++m) afr[m] = *(const bf16x8*)&A1[aBase + (m + 4) * 512];
        if (base + 9 < PMAX) stage_piece(base + 9);
        PH_SYNC();
        #pragma unroll
        for (int m = 0; m < 4; ++m)
            #pragma unroll
            for (int n = 0; n < 4; ++n)
                acc[m + 4][n] = __builtin_amdgcn_mfma_f32_16x16x32_bf16(
                    afr[m], bfr[n], acc[m + 4][n], 0, 0, 0);
        PH_END(w3);
    };

    // prologue: pieces 0..5 (tile0 all + tile1 k0); need 0,1 -> vmcnt(8)
    #pragma unroll
    for (int i = 0; i < 6; ++i) stage_piece(i);
    asm volatile("s_waitcnt vmcnt(8)" ::: "memory");
    __builtin_amdgcn_s_barrier();

    for (int t = 0; t < T_ - 2; t += 2) {
        do_tile(t, 0, 8, 8);
        do_tile(t + 1, 1, 8, 8);
    }
    do_tile(T_ - 2, 0, 8, 4);
    do_tile(T_ - 1, 1, 0, -1);

    // --- epilogue ---
    float bvn[4];
    int coln[4];
    #pragma unroll
    for (int n = 0; n < 4; ++n) {
        coln[n] = bcol + wn * 64 + n * 16 + l16;
        bvn[n] = BIAS ? bias[coln[n]] : 0.f;
    }
    #pragma unroll
    for (int m = 0; m < 8; ++m) {
        #pragma unroll
        for (int q = 0; q < 4; ++q) {
            const size_t row = (size_t)brow + wm * 128 + m * 16 + l4 * 4 + q;
            #pragma unroll
            for (int n = 0; n < 4; ++n) {
                float v = acc[m][n][q] + bvn[n];
                if (ACT == 1) v = tanhf(v) + 1.0f;
                if (ACT == 2) v = 0.5f * v * (1.0f + erff(v * 0.70710678118654752f));
                const size_t idx = row * (size_t)N + coln[n];
                if (OBF16) {
                    ((u16*)Cout)[idx] = f2b(v);
                } else {
                    float* Cf = (float*)Cout;
                    if (ACCUM) v += Cf[idx];
                    if (RES)   v += b2f(res1[idx]) + res2[idx];
                    Cf[idx] = v;
                }
            }
        }
    }
}

// ---------------------------------------------------------------------------
__global__ __launch_bounds__(256)
void ln1024_bf16_kernel(const u16* __restrict__ in, u16* __restrict__ outp,
                        const float* __restrict__ g, const float* __restrict__ be) {
    const size_t base = (size_t)blockIdx.x * Dm;
    const int tid = threadIdx.x;
    ushort4 raw = *(const ushort4*)&in[base + tid * 4];
    float v0 = b2f(raw.x), v1 = b2f(raw.y), v2 = b2f(raw.z), v3 = b2f(raw.w);
    float s  = v0 + v1 + v2 + v3;
    float sq = v0 * v0 + v1 * v1 + v2 * v2 + v3 * v3;
    #pragma unroll
    for (int off = 32; off > 0; off >>= 1) {
        s  += __shfl_down(s,  off, 64);
        sq += __shfl_down(sq, off, 64);
    }
    __shared__ float rs[4], rq[4];
    const int lane = tid & 63, wv = tid >> 6;
    if (lane == 0) { rs[wv] = s; rq[wv] = sq; }
    __syncthreads();
    s  = rs[0] + rs[1] + rs[2] + rs[3];
    sq = rq[0] + rq[1] + rq[2] + rq[3];
    const float mean = s * (1.0f / 1024.0f);
    const float var  = sq * (1.0f / 1024.0f) - mean * mean;
    const float inv  = rsqrtf(var + 1e-5f);
    float4 gv = *(const float4*)&g[tid * 4];
    float4 bv = *(const float4*)&be[tid * 4];
    ushort4 o;
    o.x = f2b((v0 - mean) * inv * gv.x + bv.x);
    o.y = f2b((v1 - mean) * inv * gv.y + bv.y);
    o.z = f2b((v2 - mean) * inv * gv.z + bv.z);
    o.w = f2b((v3 - mean) * inv * gv.w + bv.w);
    *(ushort4*)&outp[base + tid * 4] = o;
}

__global__ __launch_bounds__(256)
void qprobe_kernel(const u16* __restrict__ Q, float* __restrict__ qp) {
    const int b = blockIdx.z;
    const int col = blockIdx.x * 256 + threadIdx.x;
    const int lchunk = Lq / 16;
    const int l0 = blockIdx.y * lchunk;
    const u16* p = Q + ((size_t)b * Lq + l0) * Dm + col;
    float s = 0.f;
    for (int l = 0; l < lchunk; ++l, p += Dm) s += b2f(*p);
    atomicAdd(&qp[b * Dm + col], s * (1.0f / (4096.0f * 8.0f)));
}

__global__ __launch_bounds__(256)
void logits_kernel(const u16* __restrict__ Kc, const float* __restrict__ qp,
                   float* __restrict__ score) {
    const int bh = blockIdx.y, b = bh >> 4, h = bh & 15;
    __shared__ float q[64];
    if (threadIdx.x < 64) q[threadIdx.x] = qp[b * Dm + h * 64 + threadIdx.x];
    __syncthreads();
    const int kr = blockIdx.x * 256 + threadIdx.x;
    const ushort4* krp = (const ushort4*)&Kc[((size_t)b * Lq + kr) * Dm + h * 64];
    float s = 0.f;
    #pragma unroll
    for (int i = 0; i < 16; ++i) {
        ushort4 v = krp[i];
        s += q[i * 4 + 0] * b2f(v.x) + q[i * 4 + 1] * b2f(v.y)
           + q[i * 4 + 2] * b2f(v.z) + q[i * 4 + 3] * b2f(v.w);
    }
    score[(size_t)bh * Lk1 + kr + 1] = s;
    if (blockIdx.x == 0 && threadIdx.x == 0) score[(size_t)bh * Lk1] = 0.f;
}

__global__ __launch_bounds__(256)
void softmax4097_kernel(float* __restrict__ sc) {
    __shared__ float buf[Lk1];
    __shared__ float red[8];
    const size_t base = (size_t)blockIdx.x * Lk1;
    const int tid = threadIdx.x;
    float mx = -1e30f;
    for (int i = tid; i < Lk1; i += 256) { float v = sc[base + i]; buf[i] = v; mx = fmaxf(mx, v); }
    #pragma unroll
    for (int off = 32; off > 0; off >>= 1) mx = fmaxf(mx, __shfl_down(mx, off, 64));
    const int lane = tid & 63, wv = tid >> 6;
    if (lane == 0) red[wv] = mx;
    __syncthreads();
    mx = fmaxf(fmaxf(red[0], red[1]), fmaxf(red[2], red[3]));
    float sum = 0.f;
    for (int i = tid; i < Lk1; i += 256) { float e = expf(buf[i] - mx); buf[i] = e; sum += e; }
    #pragma unroll
    for (int off = 32; off > 0; off >>= 1) sum += __shfl_down(sum, off, 64);
    if (lane == 0) red[4 + wv] = sum;
    __syncthreads();
    sum = red[4] + red[5] + red[6] + red[7];
    const float inv = 1.0f / sum;
    for (int i = tid; i < Lk1; i += 256) sc[base + i] = buf[i] * inv;
}

__global__ __launch_bounds__(256)
void kv_kernel(const u16* __restrict__ phiK, const u16* __restrict__ Vc,
               const float* __restrict__ sc, float* __restrict__ KV) {
    const int bh = blockIdx.y, b = bh >> 4, h = bh & 15;
    const int lchunk = Lq / 8;
    const int l0 = blockIdx.x * lchunk;
    __shared__ float pk[8][64];
    __shared__ float vv[8][64];
    const int i0 = (threadIdx.x >> 4) << 2;
    const int j0 = (threadIdx.x & 15) << 2;
    float acc[4][4] = {};
    for (int lb = l0; lb < l0 + lchunk; lb += 8) {
        #pragma unroll
        for (int q = 0; q < 2; ++q) {
            const int idx = threadIdx.x + q * 256;
            const int r = idx >> 6, c = idx & 63;
            const float scv = sc[(size_t)bh * Lk1 + lb + r + 1];
            const size_t off = ((size_t)b * Lq + lb + r) * Dm + h * 64 + c;
            pk[r][c] = b2f(phiK[off]) * scv;
            vv[r][c] = b2f(Vc[off]);
        }
        __syncthreads();
        #pragma unroll
        for (int r = 0; r < 8; ++r) {
            float ra[4], rb[4];
            #pragma unroll
            for (int i = 0; i < 4; ++i) ra[i] = pk[r][i0 + i];
            #pragma unroll
            for (int j = 0; j < 4; ++j) rb[j] = vv[r][j0 + j];
            #pragma unroll
            for (int i = 0; i < 4; ++i)
                #pragma unroll
                for (int j = 0; j < 4; ++j)
                    acc[i][j] = fmaf(ra[i], rb[j], acc[i][j]);
        }
        __syncthreads();
    }
    #pragma unroll
    for (int i = 0; i < 4; ++i)
        #pragma unroll
        for (int j = 0; j < 4; ++j)
            atomicAdd(&KV[((size_t)bh * 64 + i0 + i) * 64 + j0 + j], acc[i][j]);
}

__global__ __launch_bounds__(64)
void ksum_kernel(const u16* __restrict__ phiK, const float* __restrict__ sc,
                 const float* __restrict__ bfk, float* __restrict__ Ksum) {
    const int bh = blockIdx.y, b = bh >> 4, h = bh & 15;
    const int lchunk = Lq / 8;
    const int l0 = blockIdx.x * lchunk;
    const int dd = threadIdx.x;
    float s = 0.f;
    const u16* pp = &phiK[((size_t)b * Lq + l0) * Dm + h * 64 + dd];
    const float* sp = &sc[(size_t)bh * Lk1 + l0 + 1];
    for (int l = 0; l < lchunk; ++l, pp += Dm) s = fmaf(b2f(*pp), sp[l], s);
    if (blockIdx.x == 0) s += sc[(size_t)bh * Lk1] * (tanhf(bfk[h * 64 + dd]) + 1.0f);
    atomicAdd(&Ksum[bh * 64 + dd], s);
}

// ---------------------------------------------------------------------------
// MFMA attnout (unchanged from round 6)
// ---------------------------------------------------------------------------
__global__ __launch_bounds__(256, 2)
void attnout_mfma_kernel(const u16* __restrict__ phiQ, const u16* __restrict__ KVT,
                         const float* __restrict__ Ksum, u16* __restrict__ outp) {
    __shared__ u16 pqs[256 * 64];
    __shared__ float kss[64];
    __shared__ float dns[256];
    const int bh = blockIdx.y, b = bh >> 4, h = bh & 15;
    const int l0 = blockIdx.x * 256;
    const int tid = threadIdx.x;
    const int l = tid & 63, w = tid >> 6;
    const int l16 = l & 15, l4 = l >> 4;

    bf16x8 bfr[4][2];
    {
        const u16* kb = KVT + (size_t)bh * 4096;
        #pragma unroll
        for (int n = 0; n < 4; ++n)
            #pragma unroll
            for (int kk = 0; kk < 2; ++kk)
                bfr[n][kk] = *(const bf16x8*)&kb[(n * 16 + l16) * 64 + kk * 32 + l4 * 8];
    }
    if (tid < 64) kss[tid] = Ksum[bh * 64 + tid];

    {
        const int rsub = tid >> 3;
        const int ssrc = ((tid & 7) ^ (rsub & 7)) * 8;
        u16* ldst = &pqs[(size_t)tid * 8];
        #pragma unroll
        for (int j = 0; j < 8; ++j) {
            const u16* g = phiQ + (((size_t)(b * Lq + l0 + j * 32 + rsub)) << 10)
                          + h * 64 + ssrc;
            GLL16(g, ldst + j * 2048);
        }
    }
    __syncthreads();

    {
        const int r7 = tid & 7;
        float s = 0.f;
        #pragma unroll
        for (int sl = 0; sl < 8; ++sl) {
            bf16x8 v = *(const bf16x8*)&pqs[tid * 64 + ((sl ^ r7) << 3)];
            #pragma unroll
            for (int j = 0; j < 8; ++j) s = fmaf(b2f(((u16*)&v)[j]), kss[sl * 8 + j], s);
        }
        dns[tid] = 1.0f / (s + 1e-6f);
    }

    f32x4 acc[4][4];
    const f32x4 zf = {0.f, 0.f, 0.f, 0.f};
    #pragma unroll
    for (int m = 0; m < 4; ++m)
        #pragma unroll
        for (int n = 0; n < 4; ++n) acc[m][n] = zf;
    #pragma unroll
    for (int kk = 0; kk < 2; ++kk) {
        bf16x8 afr[4];
        #pragma unroll
        for (int m = 0; m < 4; ++m) {
            const int row = w * 64 + m * 16 + l16;
            afr[m] = *(const bf16x8*)&pqs[row * 64 + (((kk * 4 + l4) ^ (row & 7)) << 3)];
        }
        #pragma unroll
        for (int m = 0; m < 4; ++m)
            #pragma unroll
            for (int n = 0; n < 4; ++n)
                acc[m][n] = __builtin_amdgcn_mfma_f32_16x16x32_bf16(
                    afr[m], bfr[n][kk], acc[m][n], 0, 0, 0);
    }
    __syncthreads();

    #pragma unroll
    for (int m = 0; m < 4; ++m) {
        #pragma unroll
        for (int q = 0; q < 4; ++q) {
            const int rl = w * 64 + m * 16 + l4 * 4 + q;
            const float dn = dns[rl];
            const size_t rowg = ((size_t)(b * Lq + l0 + rl)) << 10;
            #pragma unroll
            for (int n = 0; n < 4; ++n)
                outp[rowg + h * 64 + n * 16 + l16] = f2b(acc[m][n][q] * dn);
        }
    }
}

// ---------------------------------------------------------------------------
extern "C" void kernel_launch(void* const* d_in, const int* in_sizes, int n_in,
                              void* d_out, int out_size, void* d_ws, size_t ws_size,
                              hipStream_t stream) {
    const float* x     = (const float*)d_in[0];
    const float* Wq    = (const float*)d_in[1];
    const float* bq    = (const float*)d_in[2];
    const float* gq    = (const float*)d_in[3];
    const float* betaq = (const float*)d_in[4];
    const float* Wk    = (const float*)d_in[5];
    const float* bk    = (const float*)d_in[6];
    const float* gk    = (const float*)d_in[7];
    const float* betak = (const float*)d_in[8];
    const float* Wv    = (const float*)d_in[9];
    const float* bv    = (const float*)d_in[10];
    const float* gv    = (const float*)d_in[11];
    const float* betav = (const float*)d_in[12];
    const float* Wfq   = (const float*)d_in[13];
    const float* bfq   = (const float*)d_in[14];
    const float* Wfk   = (const float*)d_in[15];
    const float* bfk   = (const float*)d_in[16];
    const float* ga    = (const float*)d_in[17];
    const float* ba    = (const float*)d_in[18];
    const float* W1    = (const float*)d_in[19];
    const float* b1    = (const float*)d_in[20];
    const float* W2    = (const float*)d_in[21];
    const float* b2    = (const float*)d_in[22];
    float* outp = (float*)d_out;

    uint8_t* wsb = (uint8_t*)d_ws;
    size_t off = 0;
    auto alloc = [&](size_t bytes) { void* p = wsb + off; off += bytes; return p; };
    const size_t Md = (size_t)Mrows * Dm;
    u16* B0   = (u16*)alloc(Md * 2);
    u16* B1   = (u16*)alloc(Md * 2);
    u16* B2   = (u16*)alloc(Md * 2);
    u16* Wtq  = (u16*)alloc((size_t)Dm * Dm * 2);
    u16* Wtk  = (u16*)alloc((size_t)Dm * Dm * 2);
    u16* Wtv  = (u16*)alloc((size_t)Dm * Dm * 2);
    u16* Wtfq = (u16*)alloc((size_t)Dm * Dm * 2);
    u16* Wtfk = (u16*)alloc((size_t)Dm * Dm * 2);
    u16* Wt1  = (u16*)alloc((size_t)Dm * Dmlp * 2);
    u16* Wt2  = (u16*)alloc((size_t)Dm * Dmlp * 2);
    float* qp    = (float*)alloc(4096 * 4);
    float* KV    = (float*)alloc((size_t)64 * 64 * 64 * 4);
    float* Ksum  = (float*)alloc(4096 * 4);
    float* score = (float*)alloc((size_t)64 * Lk1 * 4);
    u16* KVT     = (u16*)alloc((size_t)64 * 64 * 64 * 2);
    u16* PK = (u16*)outp;
    u16* PQ = (u16*)outp + Md;

    const dim3 blk(256);
    const dim3 blk512(512);
    const dim3 gA(256);   // (16384/256)*(1024/256)
    const dim3 gM(512);   // (16384/256)*(2048/256)

    cvt_bf16_kernel<<<2048, blk, 0, stream>>>(x, B0, (int)Md);
    transpose_bf16_kernel<<<dim3(16, 16), blk, 0, stream>>>(Wq,  Wtq,  Dm, Dm);
    transpose_bf16_kernel<<<dim3(16, 16), blk, 0, stream>>>(Wk,  Wtk,  Dm, Dm);
    transpose_bf16_kernel<<<dim3(16, 16), blk, 0, stream>>>(Wv,  Wtv,  Dm, Dm);
    transpose_bf16_kernel<<<dim3(16, 16), blk, 0, stream>>>(Wfq, Wtfq, Dm, Dm);
    transpose_bf16_kernel<<<dim3(16, 16), blk, 0, stream>>>(Wfk, Wtfk, Dm, Dm);
    transpose_bf16_kernel<<<dim3(64, 16), blk, 0, stream>>>(W1,  Wt1,  Dm, Dmlp);
    transpose_bf16_kernel<<<dim3(16, 64), blk, 0, stream>>>(W2,  Wt2,  Dmlp, Dm);
    {
        const int nz = 4096 + 64 * 64 * 64 + 4096;
        zero_kernel<<<(nz + 255) / 256, blk, 0, stream>>>(qp, nz);
    }

    // 1) Q = LN(x@Wq+bq) -> B1 ; K = LN(x@Wk+bk) -> B2
    mfma_gemm256<0, false, false, true, true><<<gA, blk512, 0, stream>>>(
        B0, Dm, Wtq, Dm, bq, B1, nullptr, nullptr, Mrows, Dm, Dm);
    ln1024_bf16_kernel<<<Mrows, blk, 0, stream>>>(B1, B1, gq, betaq);
    mfma_gemm256<0, false, false, true, true><<<gA, blk512, 0, stream>>>(
        B0, Dm, Wtk, Dm, bk, B2, nullptr, nullptr, Mrows, Dm, Dm);
    ln1024_bf16_kernel<<<Mrows, blk, 0, stream>>>(B2, B2, gk, betak);

    // 2) probe softmax gating
    qprobe_kernel<<<dim3(Dm / 256, 16, Bc), blk, 0, stream>>>(B1, qp);
    logits_kernel<<<dim3(Lq / 256, 64), blk, 0, stream>>>(B2, qp, score);
    softmax4097_kernel<<<64, blk, 0, stream>>>(score);

    // 3) phiK -> PK ; phiQ -> PQ
    mfma_gemm256<1, false, false, true, true><<<gA, blk512, 0, stream>>>(
        B2, Dm, Wtfk, Dm, bfk, PK, nullptr, nullptr, Mrows, Dm, Dm);
    mfma_gemm256<1, false, false, true, true><<<gA, blk512, 0, stream>>>(
        B1, Dm, Wtfq, Dm, bfq, PQ, nullptr, nullptr, Mrows, Dm, Dm);

    // 4) V = LN(x@Wv+bv) -> B1
    mfma_gemm256<0, false, false, true, true><<<gA, blk512, 0, stream>>>(
        B0, Dm, Wtv, Dm, bv, B1, nullptr, nullptr, Mrows, Dm, Dm);
    ln1024_bf16_kernel<<<Mrows, blk, 0, stream>>>(B1, B1, gv, betav);

    // 5) KV / Ksum, then KV -> KVT bf16
    kv_kernel<<<dim3(8, 64), blk, 0, stream>>>(PK, B1, score, KV);
    ksum_kernel<<<dim3(8, 64), dim3(64), 0, stream>>>(PK, score, bfk, Ksum);
    kvt_cvt_kernel<<<64, blk, 0, stream>>>(KV, KVT);

    // 6) attention out (MFMA) -> B2, attn LN -> a (in B2)
    attnout_mfma_kernel<<<dim3(Lq / 256, 64), blk, 0, stream>>>(PQ, KVT, Ksum, B2);
    ln1024_bf16_kernel<<<Mrows, blk, 0, stream>>>(B2, B2, ga, ba);

    // 7) MLP, 2 chunks of 2048 hidden (H1 overlays B0+B1)
    u16* H1 = B0;
    for (int c = 0; c < 2; ++c) {
        mfma_gemm256<2, false, false, true, true><<<gM, blk512, 0, stream>>>(
            B2, Dm, Wt1 + (size_t)c * 2048 * Dm, Dm, b1 + c * 2048,
            H1, nullptr, nullptr, Mrows, 2048, Dm);
        if (c == 0) {
            mfma_gemm256<0, false, false, true, false><<<gA, blk512, 0, stream>>>(
                H1, 2048, Wt2 + (size_t)c * 2048, Dmlp, b2,
                outp, nullptr, nullptr, Mrows, Dm, 2048);
        } else {
            mfma_gemm256<0, true, true, false, false><<<gA, blk512, 0, stream>>>(
                H1, 2048, Wt2 + (size_t)c * 2048, Dmlp, nullptr,
                outp, B2, x, Mrows, Dm, 2048);
        }
    }
}